// Round 9
// baseline (596.150 us; speedup 1.0000x reference)
//
#include <hip/hip_runtime.h>
#include <hip/hip_bf16.h>
#include <math.h>

// Fused conv3x3(64->64) + bias + min_k + tanh(tanh()) via bf16 MFMA implicit GEMM.
// x: [16,64,256,256] f32, w: [64,64,3,3] f32, b: [64] f32, out: [16,1,256,256] f32
//
// Round 15: register-resident software pipeline on the barrier-free NHWC conv.
//   r14 post-mortem: spill-free (WRITE 4.6MB) and cache-hot (FETCH 66MB) but
//   latency-bound: VGPR_Count=80 shows the compiler issues loads per-step and
//   waits (~400cyc) before each 16-MFMA cluster (~78cyc) -> MfmaUtil 16.6%.
//   No barriers remain, so manual pipelining CAN work here (r9/r10 failed on
//   __syncthreads vmcnt drains, not on the technique):
//   - af[6][3] (72 regs): ALL 18 A-frags issued as one burst per kc chunk.
//   - bf[2][4] (32 regs): B double-buffered one (tap,kc) step ahead.
//   - kc-boundary overlap: af[*][s]@kc1 refilled right after tap (2,s)@kc0
//     (frags dead from there) -> ~2 taps of latency covering.
//   - sched_barrier(0) pins: loads can't sink past MFMA cluster, MFMAs can't
//     hoist; 2 pins/step (phase granularity, not per-inst).
//   - __launch_bounds__(256,2): 256-reg cap for ~190 live (acc 64 + af 72 +
//     bf 32 + addr). 2 blocks/CU: trading TLP for ILP deliberately.
//   - transpose_x: 4 px/thread via f32x4 plane reads (4x fewer load instrs).
// mfma_f32_16x16x32_bf16: A[m=lane&15][k=(lane>>4)*8+j], B[k=(lane>>4)*8+j][n=lane&15],
//                         C/D col=lane&15, row=(lane>>4)*4+reg (HW-verified r2-r14).

typedef __bf16 bf16x8 __attribute__((ext_vector_type(8)));
typedef float f32x4 __attribute__((ext_vector_type(4)));

#define WB_ELEMS (64 * 64 * 9)

// ws layout (bytes):
//   [0, 73728)             wB   (bf16 weights, MFMA B layout)
//   [73728, 110592)        zrow (zeroed region: 18432 bf16 = 36 KB)
//   [110592, +134217728)   xT   (NHWC bf16)
//   + 512 guard (valid-row right-edge lane reads, masked)
#define WS_ZROW_OFF   73728
#define WS_XT_OFF     110592
#define ZROW_ELEMS    18432
// OOB-row redirect: offset -(ZROW_ELEMS-64). colOff >= -64, in-row offset <= 16472,
// so redirected indices span [-18432, -1896] -> entirely inside the zeroed region.
#define ZROW_REDIR    (ZROW_ELEMS - 64)
#define WS_NEED       (110592 + 134217728 + 512)

// ---- weight prep: w[k][c][tap] -> wB[(((chunk*9+tap)*4+nt)*64+lane)*8+j] ----
// also zeroes zrow (when provided) so the conv's h-OOB redirect reads 0.
__global__ __launch_bounds__(256)
void conv_prep_w(const float* __restrict__ w, __bf16* __restrict__ wB,
                 float4* __restrict__ zrow) {
    int idx = blockIdx.x * 256 + threadIdx.x;
    if (zrow != nullptr && idx < 2304)           // 2304*16B = 36864B
        zrow[idx] = make_float4(0.f, 0.f, 0.f, 0.f);
    if (idx >= WB_ELEMS) return;
    int k   = idx / 576;
    int rem = idx - k * 576;
    int c   = rem / 9;
    int tap = rem - c * 9;
    int nt = k >> 4, m15 = k & 15;
    int chunk = c >> 5, q = (c >> 3) & 3, j = c & 7;
    int lane = (q << 4) | m15;
    wB[((((chunk * 9 + tap) * 4 + nt) * 64 + lane) << 3) + j] = (__bf16)w[idx];
}

// ---- x: NCHW f32 -> NHWC bf16. 4 px/thread: f32x4 plane reads (16B/lane), ----
// ---- 4 x 16B NHWC chunk writes per cg group.                              ----
__global__ __launch_bounds__(256)
void transpose_x(const float* __restrict__ x, __bf16* __restrict__ xT) {
    const int tid   = threadIdx.x;
    const int chunk = blockIdx.x;                 // 0..63 (1024-px chunks)
    const int n     = blockIdx.y;                 // 0..15
    const int px0   = (chunk << 10) | (tid << 2);
    const float* src = x + (size_t)n * 64 * 65536 + px0;
    __bf16* dst = xT + ((size_t)(n * 65536 + px0) << 6);
#pragma unroll
    for (int cg = 0; cg < 8; ++cg) {
        f32x4 v[8];
#pragma unroll
        for (int j = 0; j < 8; ++j)
            v[j] = *(const f32x4*)&src[(size_t)(cg * 8 + j) * 65536];
#pragma unroll
        for (int p = 0; p < 4; ++p) {
            bf16x8 o;
#pragma unroll
            for (int j = 0; j < 8; ++j)
                o[j] = (__bf16)v[j][p];
            *(bf16x8*)(dst + (size_t)p * 64 + cg * 8) = o;
        }
    }
}

// ---- LDS-free barrier-free conv, register-pipelined ----
__global__ __launch_bounds__(256, 2)
void conv_nhwc_mfma(const __bf16* __restrict__ xT,
                    const __bf16* __restrict__ wB,
                    const float* __restrict__ b,
                    float* __restrict__ out)
{
    const int tid  = threadIdx.x;
    const int lane = tid & 63;
    const int wave = tid >> 6;
    const int m15  = lane & 15;
    const int q    = lane >> 4;

    // XCD-aware bijective remap (r8-verified)
    const int lin = (int)blockIdx.x + ((int)blockIdx.y << 4) + ((int)blockIdx.z << 8);
    const int nl  = ((lin & 7) << 9) | (lin >> 3);
    const int n   = nl >> 8;
    const int h0  = ((nl >> 4) & 15) << 4;
    const int w0  = (nl & 15) << 4;

    // per-row element indices into xT; h-OOB rows redirect into the zeroed region
    int rowIdx[6];
#pragma unroll
    for (int rr = 0; rr < 6; ++rr) {
        const int gh = h0 + wave * 4 + rr - 1;
        rowIdx[rr] = ((unsigned)gh < 256u) ? (n * 256 + gh) * 16384 : -ZROW_REDIR;
    }
    // per-lane column offset: pixel (w0 + m15 - 1), channels q*8..+7
    const int colOff = (w0 + m15 - 1) * 64 + q * 8;

    // w-edge masks: s=0 invalid only for (w0==0, m15==0); s=2 only (w0==240, m15==15)
    const bool wv0 = !(w0 == 0   && m15 == 0);
    const bool wv2 = !(w0 == 240 && m15 == 15);
    bf16x8 z8;
#pragma unroll
    for (int j = 0; j < 8; ++j) z8[j] = (__bf16)0.f;

    f32x4 acc[4][4];  // [mt][nt]
#pragma unroll
    for (int mt = 0; mt < 4; ++mt)
#pragma unroll
        for (int nt = 0; nt < 4; ++nt)
            acc[mt][nt] = (f32x4){0.f, 0.f, 0.f, 0.f};

    bf16x8 af[6][3];   // all A-frags for current kc (72 VGPR)
    bf16x8 bf[2][4];   // B double-buffer (32 VGPR)

    // ---- prologue: B(tap0,kc0) first, then the 18-load A burst (kc0) ----
#pragma unroll
    for (int nt = 0; nt < 4; ++nt)
        bf[0][nt] = *(const bf16x8*)&wB[(nt << 9) + (lane << 3)];
#pragma unroll
    for (int s = 0; s < 3; ++s)
#pragma unroll
        for (int row = 0; row < 6; ++row) {
            bf16x8 a = *(const bf16x8*)&xT[rowIdx[row] + colOff + s * 64];
            if (s == 0) a = wv0 ? a : z8;
            if (s == 2) a = wv2 ? a : z8;
            af[row][s] = a;
        }
    __builtin_amdgcn_sched_barrier(0);

    // ---- 18 steps: (kc 0..1) x (tap 0..8); B prefetch 1 ahead; A refilled
    // ---- for kc=1 right after tap (2,s) of kc=0 frees af[*][s].
#pragma unroll
    for (int step = 0; step < 18; ++step) {
        const int kc  = step / 9;
        const int tap = step - kc * 9;
        const int r   = tap / 3;
        const int s   = tap - r * 3;

        if (step < 17) {
            const int stepN = step + 1;
            const int kcN   = stepN / 9;
            const int tapN  = stepN - kcN * 9;
#pragma unroll
            for (int nt = 0; nt < 4; ++nt)
                bf[stepN & 1][nt] = *(const bf16x8*)
                    &wB[kcN * 18432 + (((tapN << 2) | nt) << 9) + (lane << 3)];
        }
        __builtin_amdgcn_sched_barrier(0);

        __builtin_amdgcn_s_setprio(1);
#pragma unroll
        for (int mt = 0; mt < 4; ++mt)
#pragma unroll
            for (int nt = 0; nt < 4; ++nt)
                acc[mt][nt] = __builtin_amdgcn_mfma_f32_16x16x32_bf16(
                    af[mt + r][s], bf[step & 1][nt], acc[mt][nt], 0, 0, 0);
        __builtin_amdgcn_s_setprio(0);
        __builtin_amdgcn_sched_barrier(0);

        if (kc == 0 && r == 2) {   // steps 6,7,8: refill af[*][s] with kc=1 data
#pragma unroll
            for (int row = 0; row < 6; ++row) {
                bf16x8 a = *(const bf16x8*)&xT[rowIdx[row] + colOff + s * 64 + 32];
                if (s == 0) a = wv0 ? a : z8;
                if (s == 2) a = wv2 ? a : z8;
                af[row][s] = a;
            }
        }
    }

    // ---- epilogue: +bias, min over 64 k, tanh(tanh), store (verified r2-r14) ----
    float bias[4];
#pragma unroll
    for (int nt = 0; nt < 4; ++nt) bias[nt] = b[nt * 16 + m15];

#pragma unroll
    for (int mt = 0; mt < 4; ++mt) {
        float mv[4];
#pragma unroll
        for (int reg = 0; reg < 4; ++reg) {
            float v2 = acc[mt][0][reg] + bias[0];
            v2 = fminf(v2, acc[mt][1][reg] + bias[1]);
            v2 = fminf(v2, acc[mt][2][reg] + bias[2]);
            v2 = fminf(v2, acc[mt][3][reg] + bias[3]);
            v2 = fminf(v2, __shfl_xor(v2, 1));
            v2 = fminf(v2, __shfl_xor(v2, 2));
            v2 = fminf(v2, __shfl_xor(v2, 4));
            v2 = fminf(v2, __shfl_xor(v2, 8));
            mv[reg] = v2;
        }
        const int r2 = lane & 3;
        float v2 = mv[0];
        v2 = (r2 == 1) ? mv[1] : v2;
        v2 = (r2 == 2) ? mv[2] : v2;
        v2 = (r2 == 3) ? mv[3] : v2;
        v2 = tanhf(tanhf(v2));
        if (m15 < 4) {
            const int gh = h0 + wave * 4 + mt;
            const int gw = w0 + q * 4 + r2;
            out[((size_t)n * 256 + gh) * 256 + gw] = v2;
        }
    }
}

// ==================== fallback: exact r8 kernel (best LDS-staged, 188 us) ====================
#define SA_PX   40
#define SA_ROW  (20 * SA_PX)

__global__ __launch_bounds__(256, 3)
void conv_min_tanh_lds(const float* __restrict__ x,
                       const __bf16* __restrict__ wB,
                       const float* __restrict__ b,
                       float* __restrict__ out)
{
    __shared__ __attribute__((aligned(16))) __bf16 sA[18 * SA_ROW];

    const int tid  = threadIdx.x;
    const int lane = tid & 63;
    const int wave = tid >> 6;
    const int m15  = lane & 15;
    const int q    = lane >> 4;

    const int lin = (int)blockIdx.x + ((int)blockIdx.y << 4) + ((int)blockIdx.z << 8);
    const int nl  = ((lin & 7) << 9) | (lin >> 3);
    const int n   = nl >> 8;
    const int h0  = ((nl >> 4) & 15) << 4;
    const int w0  = (nl & 15) << 4;

    f32x4 acc[4][4];
#pragma unroll
    for (int mt = 0; mt < 4; ++mt)
#pragma unroll
        for (int nt = 0; nt < 4; ++nt)
            acc[mt][nt] = (f32x4){0.f, 0.f, 0.f, 0.f};

#pragma unroll 1
    for (int chunk = 0; chunk < 2; ++chunk) {
        if (chunk) __syncthreads();

        for (int slot = tid; slot < 360; slot += 256) {
            const int row  = slot / 20;
            const int rem  = slot - row * 20;
            const int span = rem >> 2;
            const int cg   = rem & 3;
            const int gh   = h0 + row - 1;
            const int gw0  = w0 - 1 + span * 4;

            f32x4 v[8];
            if ((unsigned)gh < 256u) {
                const float* src = x + (size_t)(n * 64 + chunk * 32 + cg * 8) * 65536
                                     + (size_t)gh * 256;
                if (gw0 >= 0 && gw0 <= 252) {
#pragma unroll
                    for (int j = 0; j < 8; ++j)
                        v[j] = *(const f32x4*)&src[(size_t)j * 65536 + gw0];
                } else {
#pragma unroll
                    for (int j = 0; j < 8; ++j)
#pragma unroll
                        for (int i = 0; i < 4; ++i) {
                            const int gw = gw0 + i;
                            v[j][i] = ((unsigned)gw < 256u) ? src[(size_t)j * 65536 + gw] : 0.f;
                        }
                }
            } else {
#pragma unroll
                for (int j = 0; j < 8; ++j)
                    v[j] = (f32x4){0.f, 0.f, 0.f, 0.f};
            }
            __bf16* wp = &sA[row * SA_ROW + (span * 4) * SA_PX + cg * 8];
#pragma unroll
            for (int i = 0; i < 4; ++i) {
                bf16x8 o;
                o[0] = (__bf16)v[0][i]; o[1] = (__bf16)v[1][i];
                o[2] = (__bf16)v[2][i]; o[3] = (__bf16)v[3][i];
                o[4] = (__bf16)v[4][i]; o[5] = (__bf16)v[5][i];
                o[6] = (__bf16)v[6][i]; o[7] = (__bf16)v[7][i];
                *(bf16x8*)&wp[i * SA_PX] = o;
            }
        }
        __syncthreads();

        const __bf16* wBc = wB + chunk * 18432;
#pragma unroll
        for (int r = 0; r < 3; ++r) {
#pragma unroll
            for (int s2 = 0; s2 < 3; ++s2) {
                const int tap = r * 3 + s2;
                bf16x8 bf4[4], a4[4];
#pragma unroll
                for (int nt = 0; nt < 4; ++nt)
                    bf4[nt] = *(const bf16x8*)&wBc[(((tap << 2) | nt) << 9) | (lane << 3)];
#pragma unroll
                for (int mt = 0; mt < 4; ++mt)
                    a4[mt] = *(const bf16x8*)
                        &sA[(wave * 4 + mt + r) * SA_ROW + (m15 + s2) * SA_PX + q * 8];
#pragma unroll
                for (int mt = 0; mt < 4; ++mt)
#pragma unroll
                    for (int nt = 0; nt < 4; ++nt)
                        acc[mt][nt] = __builtin_amdgcn_mfma_f32_16x16x32_bf16(
                            a4[mt], bf4[nt], acc[mt][nt], 0, 0, 0);
            }
        }
    }

    float bias[4];
#pragma unroll
    for (int nt = 0; nt < 4; ++nt) bias[nt] = b[nt * 16 + m15];

#pragma unroll
    for (int mt = 0; mt < 4; ++mt) {
        float mv[4];
#pragma unroll
        for (int reg = 0; reg < 4; ++reg) {
            float v2 = acc[mt][0][reg] + bias[0];
            v2 = fminf(v2, acc[mt][1][reg] + bias[1]);
            v2 = fminf(v2, acc[mt][2][reg] + bias[2]);
            v2 = fminf(v2, acc[mt][3][reg] + bias[3]);
            v2 = fminf(v2, __shfl_xor(v2, 1));
            v2 = fminf(v2, __shfl_xor(v2, 2));
            v2 = fminf(v2, __shfl_xor(v2, 4));
            v2 = fminf(v2, __shfl_xor(v2, 8));
            mv[reg] = v2;
        }
        const int r2 = lane & 3;
        float v2 = mv[0];
        v2 = (r2 == 1) ? mv[1] : v2;
        v2 = (r2 == 2) ? mv[2] : v2;
        v2 = (r2 == 3) ? mv[3] : v2;
        v2 = tanhf(tanhf(v2));
        if (m15 < 4) {
            const int pix = q * 4 + r2;
            const int gh  = h0 + wave * 4 + mt;
            const int gw  = w0 + pix;
            out[((size_t)n * 256 + gh) * 256 + gw] = v2;
        }
    }
}

extern "C" void kernel_launch(void* const* d_in, const int* in_sizes, int n_in,
                              void* d_out, int out_size, void* d_ws, size_t ws_size,
                              hipStream_t stream) {
    const float* x = (const float*)d_in[0];
    const float* w = (const float*)d_in[1];
    const float* b = (const float*)d_in[2];
    float* out = (float*)d_out;
    __bf16* wB = (__bf16*)d_ws;

    if (ws_size >= (size_t)WS_NEED) {
        float4* zrow = (float4*)((char*)d_ws + WS_ZROW_OFF);
        __bf16* xT   = (__bf16*)((char*)d_ws + WS_XT_OFF);
        conv_prep_w<<<dim3(144), dim3(256), 0, stream>>>(w, wB, zrow);
        transpose_x<<<dim3(64, 16), dim3(256), 0, stream>>>(x, xT);
        conv_nhwc_mfma<<<dim3(16, 16, 16), dim3(256), 0, stream>>>(xT, wB, b, out);
    } else {
        conv_prep_w<<<dim3(144), dim3(256), 0, stream>>>(w, wB, nullptr);
        conv_min_tanh_lds<<<dim3(16, 16, 16), dim3(256), 0, stream>>>(x, wB, b, out);
    }
}

// Round 10
// 512.758 us; speedup vs baseline: 1.1626x; 1.1626x over previous
//
#include <hip/hip_runtime.h>
#include <hip/hip_bf16.h>
#include <math.h>

// Fused conv3x3(64->64) + bias + min_k + tanh(tanh()) via bf16 MFMA implicit GEMM.
// x: [16,64,256,256] f32, w: [64,64,3,3] f32, b: [64] f32, out: [16,1,256,256] f32
//
// Round 16: revert transpose to r14's 1px/thread (r15's 4px/thread write
// pattern scattered 16B stores at 512B lane stride -> WRITE_SIZE 276MB (2.2x
// amplification), 214us vs 84us). Conv kernel UNCHANGED from r15 (the af/bf
// register pipeline worked: conv 191 -> ~90-100us by bench arithmetic).
//   Design (r11-r15):
//   - transpose_x: x[n][c][h][w] f32 -> xT[n][h][w][c] bf16 (128 MB in ws).
//     1 px/thread: 64 coalesced plane reads, 8x16B writes filling the px's
//     128B line back-to-back (merges in L2; ~84us measured r13/r14).
//   - conv_nhwc_mfma: LDS-free, barrier-free; af[6][3] A-frags burst-loaded
//     per kc chunk, bf[2][4] B double-buffer, kc-boundary refill overlap,
//     sched_barrier(0) phase pins, setprio around MFMA clusters,
//     __launch_bounds__(256,2). A-frags from xT lines, B from L2-hot wB.
//   - ws_size guard: needs ~128.1 MB; falls back to exact r8 kernel (188us).
// mfma_f32_16x16x32_bf16: A[m=lane&15][k=(lane>>4)*8+j], B[k=(lane>>4)*8+j][n=lane&15],
//                         C/D col=lane&15, row=(lane>>4)*4+reg (HW-verified r2-r15).

typedef __bf16 bf16x8 __attribute__((ext_vector_type(8)));
typedef float f32x4 __attribute__((ext_vector_type(4)));

#define WB_ELEMS (64 * 64 * 9)

// ws layout (bytes):
//   [0, 73728)             wB   (bf16 weights, MFMA B layout)
//   [73728, 110592)        zrow (zeroed region: 18432 bf16 = 36 KB)
//   [110592, +134217728)   xT   (NHWC bf16)
//   + 512 guard (valid-row right-edge lane reads, masked)
#define WS_ZROW_OFF   73728
#define WS_XT_OFF     110592
#define ZROW_ELEMS    18432
// OOB-row redirect: offset -(ZROW_ELEMS-64). colOff >= -64, in-row offset <= 16472,
// so redirected indices span [-18432, -1896] -> entirely inside the zeroed region.
#define ZROW_REDIR    (ZROW_ELEMS - 64)
#define WS_NEED       (110592 + 134217728 + 512)

// ---- weight prep: w[k][c][tap] -> wB[(((chunk*9+tap)*4+nt)*64+lane)*8+j] ----
// also zeroes zrow (when provided) so the conv's h-OOB redirect reads 0.
__global__ __launch_bounds__(256)
void conv_prep_w(const float* __restrict__ w, __bf16* __restrict__ wB,
                 float4* __restrict__ zrow) {
    int idx = blockIdx.x * 256 + threadIdx.x;
    if (zrow != nullptr && idx < 2304)           // 2304*16B = 36864B
        zrow[idx] = make_float4(0.f, 0.f, 0.f, 0.f);
    if (idx >= WB_ELEMS) return;
    int k   = idx / 576;
    int rem = idx - k * 576;
    int c   = rem / 9;
    int tap = rem - c * 9;
    int nt = k >> 4, m15 = k & 15;
    int chunk = c >> 5, q = (c >> 3) & 3, j = c & 7;
    int lane = (q << 4) | m15;
    wB[((((chunk * 9 + tap) * 4 + nt) * 64 + lane) << 3) + j] = (__bf16)w[idx];
}

// ---- x: NCHW f32 -> NHWC bf16. 1 px/thread: 64 coalesced plane reads, ----
// ---- one full 128-B contiguous line write per thread (r13/r14, ~84us). ----
__global__ __launch_bounds__(256)
void transpose_x(const float* __restrict__ x, __bf16* __restrict__ xT) {
    const int tid   = threadIdx.x;
    const int chunk = blockIdx.x;                 // 0..255 (px chunks of 256)
    const int n     = blockIdx.y;                 // 0..15
    const int px    = (chunk << 8) | tid;
    const float* src = x + (size_t)n * 64 * 65536 + px;
    __bf16* dst = xT + ((size_t)(n * 65536 + px) << 6);
#pragma unroll
    for (int cg = 0; cg < 8; ++cg) {
        float f[8];
#pragma unroll
        for (int j = 0; j < 8; ++j)
            f[j] = src[(size_t)(cg * 8 + j) * 65536];
        bf16x8 o;
#pragma unroll
        for (int j = 0; j < 8; ++j)
            o[j] = (__bf16)f[j];
        *(bf16x8*)(dst + cg * 8) = o;
    }
}

// ---- LDS-free barrier-free conv, register-pipelined (r15, unchanged) ----
__global__ __launch_bounds__(256, 2)
void conv_nhwc_mfma(const __bf16* __restrict__ xT,
                    const __bf16* __restrict__ wB,
                    const float* __restrict__ b,
                    float* __restrict__ out)
{
    const int tid  = threadIdx.x;
    const int lane = tid & 63;
    const int wave = tid >> 6;
    const int m15  = lane & 15;
    const int q    = lane >> 4;

    // XCD-aware bijective remap (r8-verified)
    const int lin = (int)blockIdx.x + ((int)blockIdx.y << 4) + ((int)blockIdx.z << 8);
    const int nl  = ((lin & 7) << 9) | (lin >> 3);
    const int n   = nl >> 8;
    const int h0  = ((nl >> 4) & 15) << 4;
    const int w0  = (nl & 15) << 4;

    // per-row element indices into xT; h-OOB rows redirect into the zeroed region
    int rowIdx[6];
#pragma unroll
    for (int rr = 0; rr < 6; ++rr) {
        const int gh = h0 + wave * 4 + rr - 1;
        rowIdx[rr] = ((unsigned)gh < 256u) ? (n * 256 + gh) * 16384 : -ZROW_REDIR;
    }
    // per-lane column offset: pixel (w0 + m15 - 1), channels q*8..+7
    const int colOff = (w0 + m15 - 1) * 64 + q * 8;

    // w-edge masks: s=0 invalid only for (w0==0, m15==0); s=2 only (w0==240, m15==15)
    const bool wv0 = !(w0 == 0   && m15 == 0);
    const bool wv2 = !(w0 == 240 && m15 == 15);
    bf16x8 z8;
#pragma unroll
    for (int j = 0; j < 8; ++j) z8[j] = (__bf16)0.f;

    f32x4 acc[4][4];  // [mt][nt]
#pragma unroll
    for (int mt = 0; mt < 4; ++mt)
#pragma unroll
        for (int nt = 0; nt < 4; ++nt)
            acc[mt][nt] = (f32x4){0.f, 0.f, 0.f, 0.f};

    bf16x8 af[6][3];   // all A-frags for current kc (72 VGPR)
    bf16x8 bf[2][4];   // B double-buffer (32 VGPR)

    // ---- prologue: B(tap0,kc0) first, then the 18-load A burst (kc0) ----
#pragma unroll
    for (int nt = 0; nt < 4; ++nt)
        bf[0][nt] = *(const bf16x8*)&wB[(nt << 9) + (lane << 3)];
#pragma unroll
    for (int s = 0; s < 3; ++s)
#pragma unroll
        for (int row = 0; row < 6; ++row) {
            bf16x8 a = *(const bf16x8*)&xT[rowIdx[row] + colOff + s * 64];
            if (s == 0) a = wv0 ? a : z8;
            if (s == 2) a = wv2 ? a : z8;
            af[row][s] = a;
        }
    __builtin_amdgcn_sched_barrier(0);

    // ---- 18 steps: (kc 0..1) x (tap 0..8); B prefetch 1 ahead; A refilled
    // ---- for kc=1 right after tap (2,s) of kc=0 frees af[*][s].
#pragma unroll
    for (int step = 0; step < 18; ++step) {
        const int kc  = step / 9;
        const int tap = step - kc * 9;
        const int r   = tap / 3;
        const int s   = tap - r * 3;

        if (step < 17) {
            const int stepN = step + 1;
            const int kcN   = stepN / 9;
            const int tapN  = stepN - kcN * 9;
#pragma unroll
            for (int nt = 0; nt < 4; ++nt)
                bf[stepN & 1][nt] = *(const bf16x8*)
                    &wB[kcN * 18432 + (((tapN << 2) | nt) << 9) + (lane << 3)];
        }
        __builtin_amdgcn_sched_barrier(0);

        __builtin_amdgcn_s_setprio(1);
#pragma unroll
        for (int mt = 0; mt < 4; ++mt)
#pragma unroll
            for (int nt = 0; nt < 4; ++nt)
                acc[mt][nt] = __builtin_amdgcn_mfma_f32_16x16x32_bf16(
                    af[mt + r][s], bf[step & 1][nt], acc[mt][nt], 0, 0, 0);
        __builtin_amdgcn_s_setprio(0);
        __builtin_amdgcn_sched_barrier(0);

        if (kc == 0 && r == 2) {   // steps 6,7,8: refill af[*][s] with kc=1 data
#pragma unroll
            for (int row = 0; row < 6; ++row) {
                bf16x8 a = *(const bf16x8*)&xT[rowIdx[row] + colOff + s * 64 + 32];
                if (s == 0) a = wv0 ? a : z8;
                if (s == 2) a = wv2 ? a : z8;
                af[row][s] = a;
            }
        }
    }

    // ---- epilogue: +bias, min over 64 k, tanh(tanh), store (verified r2-r15) ----
    float bias[4];
#pragma unroll
    for (int nt = 0; nt < 4; ++nt) bias[nt] = b[nt * 16 + m15];

#pragma unroll
    for (int mt = 0; mt < 4; ++mt) {
        float mv[4];
#pragma unroll
        for (int reg = 0; reg < 4; ++reg) {
            float v2 = acc[mt][0][reg] + bias[0];
            v2 = fminf(v2, acc[mt][1][reg] + bias[1]);
            v2 = fminf(v2, acc[mt][2][reg] + bias[2]);
            v2 = fminf(v2, acc[mt][3][reg] + bias[3]);
            v2 = fminf(v2, __shfl_xor(v2, 1));
            v2 = fminf(v2, __shfl_xor(v2, 2));
            v2 = fminf(v2, __shfl_xor(v2, 4));
            v2 = fminf(v2, __shfl_xor(v2, 8));
            mv[reg] = v2;
        }
        const int r2 = lane & 3;
        float v2 = mv[0];
        v2 = (r2 == 1) ? mv[1] : v2;
        v2 = (r2 == 2) ? mv[2] : v2;
        v2 = (r2 == 3) ? mv[3] : v2;
        v2 = tanhf(tanhf(v2));
        if (m15 < 4) {
            const int gh = h0 + wave * 4 + mt;
            const int gw = w0 + q * 4 + r2;
            out[((size_t)n * 256 + gh) * 256 + gw] = v2;
        }
    }
}

// ==================== fallback: exact r8 kernel (best LDS-staged, 188 us) ====================
#define SA_PX   40
#define SA_ROW  (20 * SA_PX)

__global__ __launch_bounds__(256, 3)
void conv_min_tanh_lds(const float* __restrict__ x,
                       const __bf16* __restrict__ wB,
                       const float* __restrict__ b,
                       float* __restrict__ out)
{
    __shared__ __attribute__((aligned(16))) __bf16 sA[18 * SA_ROW];

    const int tid  = threadIdx.x;
    const int lane = tid & 63;
    const int wave = tid >> 6;
    const int m15  = lane & 15;
    const int q    = lane >> 4;

    const int lin = (int)blockIdx.x + ((int)blockIdx.y << 4) + ((int)blockIdx.z << 8);
    const int nl  = ((lin & 7) << 9) | (lin >> 3);
    const int n   = nl >> 8;
    const int h0  = ((nl >> 4) & 15) << 4;
    const int w0  = (nl & 15) << 4;

    f32x4 acc[4][4];
#pragma unroll
    for (int mt = 0; mt < 4; ++mt)
#pragma unroll
        for (int nt = 0; nt < 4; ++nt)
            acc[mt][nt] = (f32x4){0.f, 0.f, 0.f, 0.f};

#pragma unroll 1
    for (int chunk = 0; chunk < 2; ++chunk) {
        if (chunk) __syncthreads();

        for (int slot = tid; slot < 360; slot += 256) {
            const int row  = slot / 20;
            const int rem  = slot - row * 20;
            const int span = rem >> 2;
            const int cg   = rem & 3;
            const int gh   = h0 + row - 1;
            const int gw0  = w0 - 1 + span * 4;

            f32x4 v[8];
            if ((unsigned)gh < 256u) {
                const float* src = x + (size_t)(n * 64 + chunk * 32 + cg * 8) * 65536
                                     + (size_t)gh * 256;
                if (gw0 >= 0 && gw0 <= 252) {
#pragma unroll
                    for (int j = 0; j < 8; ++j)
                        v[j] = *(const f32x4*)&src[(size_t)j * 65536 + gw0];
                } else {
#pragma unroll
                    for (int j = 0; j < 8; ++j)
#pragma unroll
                        for (int i = 0; i < 4; ++i) {
                            const int gw = gw0 + i;
                            v[j][i] = ((unsigned)gw < 256u) ? src[(size_t)j * 65536 + gw] : 0.f;
                        }
                }
            } else {
#pragma unroll
                for (int j = 0; j < 8; ++j)
                    v[j] = (f32x4){0.f, 0.f, 0.f, 0.f};
            }
            __bf16* wp = &sA[row * SA_ROW + (span * 4) * SA_PX + cg * 8];
#pragma unroll
            for (int i = 0; i < 4; ++i) {
                bf16x8 o;
                o[0] = (__bf16)v[0][i]; o[1] = (__bf16)v[1][i];
                o[2] = (__bf16)v[2][i]; o[3] = (__bf16)v[3][i];
                o[4] = (__bf16)v[4][i]; o[5] = (__bf16)v[5][i];
                o[6] = (__bf16)v[6][i]; o[7] = (__bf16)v[7][i];
                *(bf16x8*)&wp[i * SA_PX] = o;
            }
        }
        __syncthreads();

        const __bf16* wBc = wB + chunk * 18432;
#pragma unroll
        for (int r = 0; r < 3; ++r) {
#pragma unroll
            for (int s2 = 0; s2 < 3; ++s2) {
                const int tap = r * 3 + s2;
                bf16x8 bf4[4], a4[4];
#pragma unroll
                for (int nt = 0; nt < 4; ++nt)
                    bf4[nt] = *(const bf16x8*)&wBc[(((tap << 2) | nt) << 9) | (lane << 3)];
#pragma unroll
                for (int mt = 0; mt < 4; ++mt)
                    a4[mt] = *(const bf16x8*)
                        &sA[(wave * 4 + mt + r) * SA_ROW + (m15 + s2) * SA_PX + q * 8];
#pragma unroll
                for (int mt = 0; mt < 4; ++mt)
#pragma unroll
                    for (int nt = 0; nt < 4; ++nt)
                        acc[mt][nt] = __builtin_amdgcn_mfma_f32_16x16x32_bf16(
                            a4[mt], bf4[nt], acc[mt][nt], 0, 0, 0);
            }
        }
    }

    float bias[4];
#pragma unroll
    for (int nt = 0; nt < 4; ++nt) bias[nt] = b[nt * 16 + m15];

#pragma unroll
    for (int mt = 0; mt < 4; ++mt) {
        float mv[4];
#pragma unroll
        for (int reg = 0; reg < 4; ++reg) {
            float v2 = acc[mt][0][reg] + bias[0];
            v2 = fminf(v2, acc[mt][1][reg] + bias[1]);
            v2 = fminf(v2, acc[mt][2][reg] + bias[2]);
            v2 = fminf(v2, acc[mt][3][reg] + bias[3]);
            v2 = fminf(v2, __shfl_xor(v2, 1));
            v2 = fminf(v2, __shfl_xor(v2, 2));
            v2 = fminf(v2, __shfl_xor(v2, 4));
            v2 = fminf(v2, __shfl_xor(v2, 8));
            mv[reg] = v2;
        }
        const int r2 = lane & 3;
        float v2 = mv[0];
        v2 = (r2 == 1) ? mv[1] : v2;
        v2 = (r2 == 2) ? mv[2] : v2;
        v2 = (r2 == 3) ? mv[3] : v2;
        v2 = tanhf(tanhf(v2));
        if (m15 < 4) {
            const int pix = q * 4 + r2;
            const int gh  = h0 + wave * 4 + mt;
            const int gw  = w0 + pix;
            out[((size_t)n * 256 + gh) * 256 + gw] = v2;
        }
    }
}

extern "C" void kernel_launch(void* const* d_in, const int* in_sizes, int n_in,
                              void* d_out, int out_size, void* d_ws, size_t ws_size,
                              hipStream_t stream) {
    const float* x = (const float*)d_in[0];
    const float* w = (const float*)d_in[1];
    const float* b = (const float*)d_in[2];
    float* out = (float*)d_out;
    __bf16* wB = (__bf16*)d_ws;

    if (ws_size >= (size_t)WS_NEED) {
        float4* zrow = (float4*)((char*)d_ws + WS_ZROW_OFF);
        __bf16* xT   = (__bf16*)((char*)d_ws + WS_XT_OFF);
        conv_prep_w<<<dim3(144), dim3(256), 0, stream>>>(w, wB, zrow);
        transpose_x<<<dim3(256, 16), dim3(256), 0, stream>>>(x, xT);
        conv_nhwc_mfma<<<dim3(16, 16, 16), dim3(256), 0, stream>>>(xT, wB, b, out);
    } else {
        conv_prep_w<<<dim3(144), dim3(256), 0, stream>>>(w, wB, nullptr);
        conv_min_tanh_lds<<<dim3(16, 16, 16), dim3(256), 0, stream>>>(x, wB, b, out);
    }
}